// Round 12
// baseline (165.321 us; speedup 1.0000x reference)
//
#include <hip/hip_runtime.h>
#include <hip/hip_bf16.h>

// OIM MLP: T=5 gradient-descent steps on oscillator phases.
// ARCHI [2048,2048,2048,10], BATCH 256. out = concat(phi0,phi1,phi2) [256][4106] f32.
// Round 11: A/B isolation — round 10 WITHOUT the XCD remap (natural grid
// dim3(32,8,2), dou2 = z==0 && x==0). Round-6 core: 64x64 tiles, XOR swizzle,
// counted vmcnt, 32KB LDS. u2 folded into the 8 (z=0,x=0) blocks. 7 dispatches.

#define BATCH 256
#define DIM 2048
#define NCLS 10
#define OUTSTRIDE 4106
#define TSTEPS 5

typedef unsigned short ushort_t;
typedef unsigned int u32;
typedef __attribute__((ext_vector_type(8))) short short8;
typedef __attribute__((ext_vector_type(4))) float f32x4;
typedef __attribute__((ext_vector_type(4))) unsigned short ushort4v;

__device__ __forceinline__ ushort_t f2bf(float f) {
  union { float f; u32 u; } v; v.f = f;
  u32 r = v.u + 0x7FFFu + ((v.u >> 16) & 1u);
  return (ushort_t)(r >> 16);
}

// ---------------- merged setup: conversions + W1 prep + state init -----------
__global__ void setup_all(const float* __restrict__ W0, ushort_t* __restrict__ w0b,
                          const float* __restrict__ x, ushort_t* __restrict__ xb,
                          const float* __restrict__ W2, ushort_t* __restrict__ w2b,
                          const float* __restrict__ W1, ushort_t* __restrict__ w1b,
                          ushort_t* __restrict__ w1tb,
                          const float* __restrict__ phi0, const float* __restrict__ phi1,
                          const float* __restrict__ phi2, float* __restrict__ out,
                          ushort_t* __restrict__ cs0, ushort_t* __restrict__ cs1,
                          float* __restrict__ t2_0) {
  __shared__ float tile[64][65];
  int bid = blockIdx.x;
  int tid = threadIdx.x;
  if (bid < 2048) {
    int i = (bid * 256 + tid) * 8;
#pragma unroll
    for (int h = 0; h < 2; ++h) {
      float4 v = *(const float4*)&W0[i + h * 4];
      ushort4v o;
      o.x = f2bf(v.x); o.y = f2bf(v.y); o.z = f2bf(v.z); o.w = f2bf(v.w);
      *(ushort4v*)&w0b[i + h * 4] = o;
    }
  } else if (bid < 2560) {
    int i = ((bid - 2048) * 256 + tid) * 4;   // 512 blocks * 1024 = 524288
    float4 v = *(const float4*)&x[i];
    ushort4v o;
    o.x = f2bf(v.x); o.y = f2bf(v.y); o.z = f2bf(v.z); o.w = f2bf(v.w);
    *(ushort4v*)&xb[i] = o;
  } else if (bid < 2592) {
    int i = ((bid - 2560) * 256 + tid) * 4;   // 32 blocks cover 16*2048
    int r = i >> 11;
    ushort4v o;
    if (r < NCLS) {
      float4 v = *(const float4*)&W2[i];
      o.x = f2bf(v.x); o.y = f2bf(v.y); o.z = f2bf(v.z); o.w = f2bf(v.w);
    } else {
      o.x = 0; o.y = 0; o.z = 0; o.w = 0;
    }
    *(ushort4v*)&w2b[i] = o;
  } else if (bid < 3616) {
    int t = bid - 2592;                        // 1024 tiles of 64x64
    int c0 = (t & 31) * 64, r0 = (t >> 5) * 64;
    int tx = tid & 63, ty = tid >> 6;          // 64 x 4
    for (int r = ty; r < 64; r += 4) {
      float v = W1[(size_t)(r0 + r) * DIM + c0 + tx];
      tile[r][tx] = v;
      w1b[(size_t)(r0 + r) * DIM + c0 + tx] = f2bf(v);
    }
    __syncthreads();
    for (int r = ty; r < 64; r += 4)
      w1tb[(size_t)(c0 + r) * DIM + r0 + tx] = f2bf(tile[tx][r]);
  } else {
    int t = bid - 3616;                        // 4352 = 17 * 256
    int xx = t % 17, b = t / 17;
    int col = xx * 256 + tid;
    if (col >= OUTSTRIDE) return;
    int rc = (b >> 5) * 64 + (b & 31);
    float phi, s, c;
    if (col < DIM) {
      phi = phi0[(size_t)b * DIM + col];
      __sincosf(phi, &s, &c);
      cs0[(size_t)rc * DIM + col] = f2bf(c);
      cs0[(size_t)(rc + 32) * DIM + col] = f2bf(s);
    } else if (col < 2 * DIM) {
      int j = col - DIM;
      phi = phi1[(size_t)b * DIM + j];
      __sincosf(phi, &s, &c);
      cs1[(size_t)rc * DIM + j] = f2bf(c);
      cs1[(size_t)(rc + 32) * DIM + j] = f2bf(s);
    } else {
      int j = col - 2 * DIM;
      phi = phi2[b * NCLS + j];
      __sincosf(phi, &s, &c);
      t2_0[b * 32 + j] = c;
      t2_0[b * 32 + 16 + j] = s;
    }
    out[(size_t)b * OUTSTRIDE + col] = phi;
  }
}

__device__ __forceinline__ void gload16(const void* g, void* l) {
  __builtin_amdgcn_global_load_lds((const __attribute__((address_space(1))) u32*)g,
                                   (__attribute__((address_space(3))) u32*)l, 16, 0, 0);
}

// ---------------- a0 = x @ W0^T, K-split 2 -----------------------------------
__global__ __launch_bounds__(256) void gemm_a0(
    const ushort_t* __restrict__ A, const ushort_t* __restrict__ B,
    float* __restrict__ Cp) {
  int ks = blockIdx.z;
  int n0 = blockIdx.x * 64;
  int m0 = blockIdx.y * 64;
  int kbase = ks * 1024;

  __shared__ ushort_t lds[2][2][64 * 64];
  int tid = threadIdx.x, wave = tid >> 6, lane = tid & 63;
  int wr = wave >> 1, wc = wave & 1;

  f32x4 acc[2][2];
#pragma unroll
  for (int m = 0; m < 2; ++m)
#pragma unroll
    for (int n = 0; n < 2; ++n) acc[m][n] = (f32x4)0.f;

  int srow = tid >> 3;          // 0..31
  int sg = tid & 7;             // dest granule 0..7

  auto stage = [&](int buf, int k0q) {
#pragma unroll
    for (int rseg = 0; rseg < 2; ++rseg) {
      int row = rseg * 32 + srow;
      int gsrc = (sg ^ (row & 7)) * 8;
      gload16(A + (size_t)(m0 + row) * DIM + k0q + gsrc, &lds[buf][0][row * 64 + sg * 8]);
      gload16(B + (size_t)(n0 + row) * DIM + k0q + gsrc, &lds[buf][1][row * 64 + sg * 8]);
    }
  };

  stage(0, kbase);
  int cur = 0;
  for (int kt = 0; kt < 16; ++kt) {
    if (kt + 1 < 16) {
      stage(cur ^ 1, kbase + (kt + 1) * 64);
      asm volatile("s_waitcnt vmcnt(4)" ::: "memory");
    } else {
      asm volatile("s_waitcnt vmcnt(0)" ::: "memory");
    }
    __builtin_amdgcn_s_barrier();
    const ushort_t* la = lds[cur][0];
    const ushort_t* lb = lds[cur][1];
    int rowa = wr * 32 + (lane & 15);
    int rowb = wc * 32 + (lane & 15);
    int gl = lane >> 4;
#pragma unroll
    for (int kk = 0; kk < 64; kk += 32) {
      int kg = kk >> 3;
      int ga = ((gl + kg) ^ (rowa & 7)) * 8;
      int gb = ((gl + kg) ^ (rowb & 7)) * 8;
      short8 af0 = *(const short8*)&la[rowa * 64 + ga];
      short8 af1 = *(const short8*)&la[(rowa + 16) * 64 + ga];
      short8 bf0 = *(const short8*)&lb[rowb * 64 + gb];
      short8 bf1 = *(const short8*)&lb[(rowb + 16) * 64 + gb];
      acc[0][0] = __builtin_amdgcn_mfma_f32_16x16x32_bf16(af0, bf0, acc[0][0], 0, 0, 0);
      acc[0][1] = __builtin_amdgcn_mfma_f32_16x16x32_bf16(af0, bf1, acc[0][1], 0, 0, 0);
      acc[1][0] = __builtin_amdgcn_mfma_f32_16x16x32_bf16(af1, bf0, acc[1][0], 0, 0, 0);
      acc[1][1] = __builtin_amdgcn_mfma_f32_16x16x32_bf16(af1, bf1, acc[1][1], 0, 0, 0);
    }
    asm volatile("s_waitcnt lgkmcnt(0)" ::: "memory");
    __builtin_amdgcn_s_barrier();
    cur ^= 1;
  }

  float* C = Cp + (size_t)ks * BATCH * DIM;
#pragma unroll
  for (int m = 0; m < 2; ++m)
#pragma unroll
    for (int n = 0; n < 2; ++n)
#pragma unroll
      for (int r = 0; r < 4; ++r) {
        int row = m0 + wr * 32 + m * 16 + (lane >> 4) * 4 + r;
        int col = n0 + wc * 32 + n * 16 + (lane & 15);
        C[(size_t)row * DIM + col] = acc[m][n][r];
      }
}

// ---------------- fused iteration kernel (natural grid, u2 folded) -----------
// z=0: PQ = [c1;s1]@w1tb^T -> phi0 (+cs0_new); (z=0,x=0) blocks also u2/phi2.
// z=1: RS = [c0;s0]@w1b^T  -> phi1 (+cs1_new).
__global__ __launch_bounds__(256, 2) void fused_iter(
    const ushort_t* __restrict__ cs0_old, const ushort_t* __restrict__ cs1_old,
    ushort_t* __restrict__ cs0_new, ushort_t* __restrict__ cs1_new,
    const ushort_t* __restrict__ w1tb, const ushort_t* __restrict__ w1b,
    const ushort_t* __restrict__ w2b,
    const float* __restrict__ a0p,
    const float* __restrict__ b0, const float* __restrict__ k0,
    const float* __restrict__ b1, const float* __restrict__ k1,
    const float* __restrict__ b2, const float* __restrict__ k2,
    const float* __restrict__ W2, const int* __restrict__ y,
    const float* __restrict__ t2_old, float* __restrict__ t2_new,
    float* __restrict__ out) {
  const int zz = blockIdx.z;
  const int xx = blockIdx.x;
  const int g = blockIdx.y;
  const int n0 = xx * 64, m0 = g * 64;
  const bool dou2 = (zz == 0) && (xx == 0);

  const ushort_t* A = zz ? cs0_old : cs1_old;
  const ushort_t* B = zz ? w1b : w1tb;

  __shared__ ushort_t lds[2][2][4096];   // 32 KB
  int tid = threadIdx.x, wave = tid >> 6, lane = tid & 63;
  int wr = wave >> 1, wc = wave & 1;
  int fr = lane & 15, fq = lane >> 4;
  const bool u2w = dou2 && (wc == 0);    // waves 0,2 carry u2 (all 64 A-rows)

  f32x4 acc[2][2];
#pragma unroll
  for (int m = 0; m < 2; ++m)
#pragma unroll
    for (int n = 0; n < 2; ++n) acc[m][n] = (f32x4)0.f;
  f32x4 u2acc[2];
  u2acc[0] = (f32x4)0.f; u2acc[1] = (f32x4)0.f;
  short8 u2c0 = {}, u2c1 = {}, u2n0 = {}, u2n1 = {};

  int srow = tid >> 3;
  int sg = tid & 7;

  auto stage = [&](int buf, int k0q) {
#pragma unroll
    for (int rseg = 0; rseg < 2; ++rseg) {
      int row = rseg * 32 + srow;
      int gsrc = (sg ^ (row & 7)) * 8;
      gload16(A + (size_t)(m0 + row) * DIM + k0q + gsrc, &lds[buf][0][row * 64 + sg * 8]);
      gload16(B + (size_t)(n0 + row) * DIM + k0q + gsrc, &lds[buf][1][row * 64 + sg * 8]);
    }
  };

  stage(0, 0);
  if (u2w) {
    u2c0 = *(const short8*)&w2b[fr * 2048 + fq * 8];
    u2c1 = *(const short8*)&w2b[fr * 2048 + 32 + fq * 8];
  }
  int cur = 0;
  for (int kt = 0; kt < 32; ++kt) {
    if (kt + 1 < 32) {
      stage(cur ^ 1, (kt + 1) * 64);
      if (u2w) {
        u2n0 = *(const short8*)&w2b[fr * 2048 + (kt + 1) * 64 + fq * 8];
        u2n1 = *(const short8*)&w2b[fr * 2048 + (kt + 1) * 64 + 32 + fq * 8];
        __builtin_amdgcn_sched_barrier(0);
        asm volatile("s_waitcnt vmcnt(6)" ::: "memory");
      } else {
        asm volatile("s_waitcnt vmcnt(4)" ::: "memory");
      }
    } else {
      asm volatile("s_waitcnt vmcnt(0)" ::: "memory");
    }
    __builtin_amdgcn_s_barrier();
    const ushort_t* la = lds[cur][0];
    const ushort_t* lb = lds[cur][1];
    int rowa = wr * 32 + fr;
    int rowb = wc * 32 + fr;
#pragma unroll
    for (int kk = 0; kk < 64; kk += 32) {
      int kg = kk >> 3;
      int ga = ((fq + kg) ^ (rowa & 7)) * 8;
      int gb = ((fq + kg) ^ (rowb & 7)) * 8;
      short8 af0 = *(const short8*)&la[rowa * 64 + ga];
      short8 af1 = *(const short8*)&la[(rowa + 16) * 64 + ga];
      short8 bf0 = *(const short8*)&lb[rowb * 64 + gb];
      short8 bf1 = *(const short8*)&lb[(rowb + 16) * 64 + gb];
      acc[0][0] = __builtin_amdgcn_mfma_f32_16x16x32_bf16(af0, bf0, acc[0][0], 0, 0, 0);
      acc[0][1] = __builtin_amdgcn_mfma_f32_16x16x32_bf16(af0, bf1, acc[0][1], 0, 0, 0);
      acc[1][0] = __builtin_amdgcn_mfma_f32_16x16x32_bf16(af1, bf0, acc[1][0], 0, 0, 0);
      acc[1][1] = __builtin_amdgcn_mfma_f32_16x16x32_bf16(af1, bf1, acc[1][1], 0, 0, 0);
      if (u2w) {
        short8 ub = kk ? u2c1 : u2c0;
        u2acc[0] = __builtin_amdgcn_mfma_f32_16x16x32_bf16(af0, ub, u2acc[0], 0, 0, 0);
        u2acc[1] = __builtin_amdgcn_mfma_f32_16x16x32_bf16(af1, ub, u2acc[1], 0, 0, 0);
      }
    }
    if (u2w) { u2c0 = u2n0; u2c1 = u2n1; }
    asm volatile("s_waitcnt lgkmcnt(0)" ::: "memory");
    __builtin_amdgcn_s_barrier();
    cur ^= 1;
  }

  // ---- epilogue: exchange via LDS; u2 slab at float offset 4352 --------------
  float* ldsF = (float*)lds;               // [64][65] f32 in [0, 4160)
#pragma unroll
  for (int m = 0; m < 2; ++m)
#pragma unroll
    for (int n = 0; n < 2; ++n)
#pragma unroll
      for (int rr = 0; rr < 4; ++rr)
        ldsF[(wr * 32 + m * 16 + fq * 4 + rr) * 65 + wc * 32 + n * 16 + fr] = acc[m][n][rr];
  if (u2w) {
#pragma unroll
    for (int m = 0; m < 2; ++m)
      *(f32x4*)&ldsF[4352 + ((wr * 2 + m) * 64 + lane) * 4] = u2acc[m];
  }
  __syncthreads();

  int c4 = fr * 4;
  int jg = n0 + c4;
  const float* bb_ = zz ? b1 : b0;
  const float* kk_ = zz ? k1 : k0;
  f32x4 bv = *(const f32x4*)&bb_[jg];
  f32x4 kv = *(const f32x4*)&kk_[jg];
  size_t oofs = zz ? (size_t)DIM : 0;
  ushort_t* csn = zz ? cs1_new : cs0_new;

#pragma unroll
  for (int bb2 = 0; bb2 < 2; ++bb2) {
    int bl = (tid >> 4) * 2 + bb2;         // 0..31
    int b = g * 32 + bl;
    f32x4 P, Q;
#pragma unroll
    for (int i = 0; i < 4; ++i) {
      P[i] = ldsF[bl * 65 + c4 + i];
      Q[i] = ldsF[(bl + 32) * 65 + c4 + i];
    }
    f32x4 uc, us;
    if (zz == 0) {
      f32x4 av = *(const f32x4*)&a0p[(size_t)b * DIM + jg];
      f32x4 av1 = *(const f32x4*)&a0p[(size_t)BATCH * DIM + (size_t)b * DIM + jg];
      av += av1;
      uc = P + av + bv;
      us = Q;
    } else {
      f32x4 tc = (f32x4)0.f, ts = (f32x4)0.f;
#pragma unroll
      for (int q = 0; q < NCLS; ++q) {
        f32x4 wv = *(const f32x4*)&W2[q * DIM + jg];
        tc += t2_old[b * 32 + q] * wv;
        ts += t2_old[b * 32 + 16 + q] * wv;
      }
      uc = P + tc + bv;
      us = Q + ts;
    }
    float* po = &out[(size_t)b * OUTSTRIDE + oofs + jg];
    f32x4 ph = *(const f32x4*)po;
    ushort4v cv, sv;
#pragma unroll
    for (int i = 0; i < 4; ++i) {
      float sn, cn;
      __sincosf(ph[i], &sn, &cn);
      float gr = uc[i] * sn - us[i] * cn + kv[i] * 2.f * sn * cn;
      float pn = ph[i] - 0.1f * gr;
      ph[i] = pn;
      __sincosf(pn, &sn, &cn);
      cv[i] = f2bf(cn);
      sv[i] = f2bf(sn);
    }
    *(f32x4*)po = ph;
    int rc = g * 64 + bl;
    *(ushort4v*)&csn[(size_t)rc * DIM + jg] = cv;
    *(ushort4v*)&csn[(size_t)(rc + 32) * DIM + jg] = sv;
  }

  // ---- u2 reduce + phi2 update (dou2 blocks; 320 items, strided) ------------
  if (dou2) {
    for (int it = tid; it < 32 * NCLS; it += 256) {
      int bl = it / NCLS, j = it % NCLS;
      int b = g * 32 + bl;
      int r1 = bl, r2 = bl + 32;
      float u2c = ldsF[4352 + (((r1 >> 5) * 2 + ((r1 >> 4) & 1)) * 64 +
                               ((r1 >> 2) & 3) * 16 + j) * 4 + (r1 & 3)];
      float u2s = ldsF[4352 + (((r2 >> 5) * 2 + ((r2 >> 4) & 1)) * 64 +
                               ((r2 >> 2) & 3) * 16 + j) * 4 + (r2 & 3)];
      size_t oi = (size_t)b * OUTSTRIDE + 2 * DIM + j;
      float phi = out[oi];
      float sn, cn;
      __sincosf(phi, &sn, &cn);
      float y1h = (y[b] == j) ? 1.f : -1.f;
      float gr = (u2c + b2[j]) * sn - u2s * cn + k2[j] * 2.f * sn * cn
                 - 0.5f * (cn - y1h) * sn;
      float pn = phi - 0.1f * gr;
      out[oi] = pn;
      __sincosf(pn, &sn, &cn);
      t2_new[b * 32 + j] = cn;
      t2_new[b * 32 + 16 + j] = sn;
    }
  }
}

// ---------------- launch ----------------
extern "C" void kernel_launch(void* const* d_in, const int* in_sizes, int n_in,
                              void* d_out, int out_size, void* d_ws, size_t ws_size,
                              hipStream_t stream) {
  const float* x    = (const float*)d_in[0];
  const float* W0   = (const float*)d_in[1];
  const float* W1   = (const float*)d_in[2];
  const float* W2   = (const float*)d_in[3];
  const float* b0   = (const float*)d_in[4];
  const float* b1   = (const float*)d_in[5];
  const float* b2   = (const float*)d_in[6];
  const float* k0   = (const float*)d_in[7];
  const float* k1   = (const float*)d_in[8];
  const float* k2   = (const float*)d_in[9];
  const float* phi0 = (const float*)d_in[10];
  const float* phi1 = (const float*)d_in[11];
  const float* phi2 = (const float*)d_in[12];
  const int*   y    = (const int*)d_in[13];
  float* out = (float*)d_out;

  const size_t CS = (size_t)2 * BATCH * DIM;   // 512*2048 elems per cs buffer

  char* w = (char*)d_ws;
  ushort_t* w0b  = (ushort_t*)w; w += (size_t)DIM * DIM * 2;
  ushort_t* w1b  = (ushort_t*)w; w += (size_t)DIM * DIM * 2;
  ushort_t* w1tb = (ushort_t*)w; w += (size_t)DIM * DIM * 2;
  ushort_t* w2b  = (ushort_t*)w; w += (size_t)16 * DIM * 2;
  ushort_t* xb   = (ushort_t*)w; w += (size_t)BATCH * DIM * 2;
  ushort_t* csi0 = (ushort_t*)w; w += 2 * CS * 2;
  ushort_t* csi1 = (ushort_t*)w; w += 2 * CS * 2;
  float* a0p = (float*)w; w += (size_t)2 * BATCH * DIM * 4;
  float* t2  = (float*)w; w += (size_t)2 * BATCH * 32 * 4;

  setup_all<<<7968, 256, 0, stream>>>(W0, w0b, x, xb, W2, w2b, W1, w1b, w1tb,
                                      phi0, phi1, phi2, out, csi0, csi1, t2);

  gemm_a0<<<dim3(32, 4, 2), 256, 0, stream>>>(xb, w0b, a0p);

  for (int t = 0; t < TSTEPS; ++t) {
    int r = t & 1, wv = r ^ 1;
    fused_iter<<<dim3(32, 8, 2), 256, 0, stream>>>(
        csi0 + r * CS, csi1 + r * CS, csi0 + wv * CS, csi1 + wv * CS,
        w1tb, w1b, w2b, a0p, b0, k0, b1, k1, b2, k2, W2, y,
        t2 + r * BATCH * 32, t2 + wv * BATCH * 32, out);
  }
}

// Round 13
// 134.315 us; speedup vs baseline: 1.2308x; 1.2308x over previous
//
#include <hip/hip_runtime.h>
#include <hip/hip_bf16.h>

// OIM MLP: T=5 gradient-descent steps on oscillator phases.
// ARCHI [2048,2048,2048,10], BATCH 256. out = concat(phi0,phi1,phi2) [256][4106] f32.
// Round 12: exact revert to round 6 (best measured: 133.9 us). 64x64 tiles,
// XOR swizzle (involution on both sides of global_load_lds), counted-vmcnt
// double buffer, 32KB LDS, launch_bounds(256,3) -> 3 blocks/CU. Separate
// u2-GEMM slab (z=0, x==0 only). A/B history: u2-fold into GEMM = -23%
// (VGPR->occupancy), XCD remap = neutral, wave-K-split = -5%, mega = -6x.

#define BATCH 256
#define DIM 2048
#define NCLS 10
#define OUTSTRIDE 4106
#define TSTEPS 5

typedef unsigned short ushort_t;
typedef unsigned int u32;
typedef __attribute__((ext_vector_type(8))) short short8;
typedef __attribute__((ext_vector_type(4))) float f32x4;
typedef __attribute__((ext_vector_type(4))) unsigned short ushort4v;

__device__ __forceinline__ ushort_t f2bf(float f) {
  union { float f; u32 u; } v; v.f = f;
  u32 r = v.u + 0x7FFFu + ((v.u >> 16) & 1u);
  return (ushort_t)(r >> 16);
}

// ---------------- merged setup: conversions + W1 prep + state init -----------
__global__ void setup_all(const float* __restrict__ W0, ushort_t* __restrict__ w0b,
                          const float* __restrict__ x, ushort_t* __restrict__ xb,
                          const float* __restrict__ W2, ushort_t* __restrict__ w2b,
                          const float* __restrict__ W1, ushort_t* __restrict__ w1b,
                          ushort_t* __restrict__ w1tb,
                          const float* __restrict__ phi0, const float* __restrict__ phi1,
                          const float* __restrict__ phi2, float* __restrict__ out,
                          ushort_t* __restrict__ cs0, ushort_t* __restrict__ cs1,
                          float* __restrict__ t2_0) {
  __shared__ float tile[64][65];
  int bid = blockIdx.x;
  int tid = threadIdx.x;
  if (bid < 2048) {
    int i = (bid * 256 + tid) * 8;
#pragma unroll
    for (int h = 0; h < 2; ++h) {
      float4 v = *(const float4*)&W0[i + h * 4];
      ushort4v o;
      o.x = f2bf(v.x); o.y = f2bf(v.y); o.z = f2bf(v.z); o.w = f2bf(v.w);
      *(ushort4v*)&w0b[i + h * 4] = o;
    }
  } else if (bid < 2560) {
    int i = ((bid - 2048) * 256 + tid) * 4;   // 512 blocks * 1024 = 524288
    float4 v = *(const float4*)&x[i];
    ushort4v o;
    o.x = f2bf(v.x); o.y = f2bf(v.y); o.z = f2bf(v.z); o.w = f2bf(v.w);
    *(ushort4v*)&xb[i] = o;
  } else if (bid < 2688) {
    int i = ((bid - 2560) * 256 + tid) * 4;   // 128 blocks cover 64*2048
    int r = i >> 11;
    ushort4v o;
    if (r < NCLS) {
      float4 v = *(const float4*)&W2[i];
      o.x = f2bf(v.x); o.y = f2bf(v.y); o.z = f2bf(v.z); o.w = f2bf(v.w);
    } else {
      o.x = 0; o.y = 0; o.z = 0; o.w = 0;
    }
    *(ushort4v*)&w2b[i] = o;
  } else if (bid < 3712) {
    int t = bid - 2688;                        // 1024 tiles of 64x64
    int c0 = (t & 31) * 64, r0 = (t >> 5) * 64;
    int tx = tid & 63, ty = tid >> 6;          // 64 x 4
    for (int r = ty; r < 64; r += 4) {
      float v = W1[(size_t)(r0 + r) * DIM + c0 + tx];
      tile[r][tx] = v;
      w1b[(size_t)(r0 + r) * DIM + c0 + tx] = f2bf(v);
    }
    __syncthreads();
    for (int r = ty; r < 64; r += 4)
      w1tb[(size_t)(c0 + r) * DIM + r0 + tx] = f2bf(tile[tx][r]);
  } else {
    int t = bid - 3712;                        // 4352 = 17 * 256
    int xx = t % 17, b = t / 17;
    int col = xx * 256 + tid;
    if (col >= OUTSTRIDE) return;
    int rc = (b >> 5) * 64 + (b & 31);
    float phi, s, c;
    if (col < DIM) {
      phi = phi0[(size_t)b * DIM + col];
      __sincosf(phi, &s, &c);
      cs0[(size_t)rc * DIM + col] = f2bf(c);
      cs0[(size_t)(rc + 32) * DIM + col] = f2bf(s);
    } else if (col < 2 * DIM) {
      int j = col - DIM;
      phi = phi1[(size_t)b * DIM + j];
      __sincosf(phi, &s, &c);
      cs1[(size_t)rc * DIM + j] = f2bf(c);
      cs1[(size_t)(rc + 32) * DIM + j] = f2bf(s);
    } else {
      int j = col - 2 * DIM;
      phi = phi2[b * NCLS + j];
      __sincosf(phi, &s, &c);
      t2_0[b * 32 + j] = c;
      t2_0[b * 32 + 16 + j] = s;
    }
    out[(size_t)b * OUTSTRIDE + col] = phi;
  }
}

// ---------------- shared GEMM machinery (64x64 tile, BK=64, 4 waves) ---------
// LDS tile [64 rows][8 granules of 16B]; granule g of row r holds GLOBAL
// granule g ^ (r&7) (pre-swizzled source; linear gload_lds dest; swizzled read).
__device__ __forceinline__ void gload16(const void* g, void* l) {
  __builtin_amdgcn_global_load_lds((const __attribute__((address_space(1))) u32*)g,
                                   (__attribute__((address_space(3))) u32*)l, 16, 0, 0);
}

// ---------------- a0 = x @ W0^T, K-split 2 -----------------------------------
__global__ __launch_bounds__(256) void gemm_a0(
    const ushort_t* __restrict__ A, const ushort_t* __restrict__ B,
    float* __restrict__ Cp) {
  int ks = blockIdx.z;
  int n0 = blockIdx.x * 64;
  int m0 = blockIdx.y * 64;
  int kbase = ks * 1024;

  __shared__ ushort_t lds[2][2][64 * 64];
  int tid = threadIdx.x, wave = tid >> 6, lane = tid & 63;
  int wr = wave >> 1, wc = wave & 1;

  f32x4 acc[2][2];
#pragma unroll
  for (int m = 0; m < 2; ++m)
#pragma unroll
    for (int n = 0; n < 2; ++n) acc[m][n] = (f32x4)0.f;

  int srow = tid >> 3;          // 0..31
  int sg = tid & 7;             // dest granule 0..7

  auto stage = [&](int buf, int k0q) {
#pragma unroll
    for (int rseg = 0; rseg < 2; ++rseg) {
      int row = rseg * 32 + srow;
      int gsrc = (sg ^ (row & 7)) * 8;
      gload16(A + (size_t)(m0 + row) * DIM + k0q + gsrc, &lds[buf][0][row * 64 + sg * 8]);
      gload16(B + (size_t)(n0 + row) * DIM + k0q + gsrc, &lds[buf][1][row * 64 + sg * 8]);
    }
  };

  stage(0, kbase);
  int cur = 0;
  for (int kt = 0; kt < 16; ++kt) {
    if (kt + 1 < 16) {
      stage(cur ^ 1, kbase + (kt + 1) * 64);
      asm volatile("s_waitcnt vmcnt(4)" ::: "memory");   // cur's 4 done; 4 in flight
    } else {
      asm volatile("s_waitcnt vmcnt(0)" ::: "memory");
    }
    __builtin_amdgcn_s_barrier();
    const ushort_t* la = lds[cur][0];
    const ushort_t* lb = lds[cur][1];
    int rowa = wr * 32 + (lane & 15);
    int rowb = wc * 32 + (lane & 15);
    int gl = lane >> 4;
#pragma unroll
    for (int kk = 0; kk < 64; kk += 32) {
      int kg = kk >> 3;
      int ga = ((gl + kg) ^ (rowa & 7)) * 8;
      int gb = ((gl + kg) ^ (rowb & 7)) * 8;
      short8 af0 = *(const short8*)&la[rowa * 64 + ga];
      short8 af1 = *(const short8*)&la[(rowa + 16) * 64 + ga];
      short8 bf0 = *(const short8*)&lb[rowb * 64 + gb];
      short8 bf1 = *(const short8*)&lb[(rowb + 16) * 64 + gb];
      acc[0][0] = __builtin_amdgcn_mfma_f32_16x16x32_bf16(af0, bf0, acc[0][0], 0, 0, 0);
      acc[0][1] = __builtin_amdgcn_mfma_f32_16x16x32_bf16(af0, bf1, acc[0][1], 0, 0, 0);
      acc[1][0] = __builtin_amdgcn_mfma_f32_16x16x32_bf16(af1, bf0, acc[1][0], 0, 0, 0);
      acc[1][1] = __builtin_amdgcn_mfma_f32_16x16x32_bf16(af1, bf1, acc[1][1], 0, 0, 0);
    }
    asm volatile("s_waitcnt lgkmcnt(0)" ::: "memory");   // reads complete
    __builtin_amdgcn_s_barrier();                        // safe to overwrite
    cur ^= 1;
  }

  float* C = Cp + (size_t)ks * BATCH * DIM;
#pragma unroll
  for (int m = 0; m < 2; ++m)
#pragma unroll
    for (int n = 0; n < 2; ++n)
#pragma unroll
      for (int r = 0; r < 4; ++r) {
        int row = m0 + wr * 32 + m * 16 + (lane >> 4) * 4 + r;
        int col = n0 + wc * 32 + n * 16 + (lane & 15);
        C[(size_t)row * DIM + col] = acc[m][n][r];
      }
}

// ---------------- fused iteration kernel -------------------------------------
// z=0: u2 = [c1;s1]@w2b^T  -> phi2 update (+t2_new). only blockIdx.x==0.
// z=1: PQ = [c1;s1]@w1tb^T -> phi0 update (+cs0_new).
// z=2: RS = [c0;s0]@w1b^T  -> phi1 update (+cs1_new).
__global__ __launch_bounds__(256, 3) void fused_iter(
    const ushort_t* __restrict__ cs0_old, const ushort_t* __restrict__ cs1_old,
    ushort_t* __restrict__ cs0_new, ushort_t* __restrict__ cs1_new,
    const ushort_t* __restrict__ w1tb, const ushort_t* __restrict__ w1b,
    const ushort_t* __restrict__ w2b,
    const float* __restrict__ a0p,
    const float* __restrict__ b0, const float* __restrict__ k0,
    const float* __restrict__ b1, const float* __restrict__ k1,
    const float* __restrict__ b2, const float* __restrict__ k2,
    const float* __restrict__ W2, const int* __restrict__ y,
    const float* __restrict__ t2_old, float* __restrict__ t2_new,
    float* __restrict__ out) {
  int z = blockIdx.z;
  if (z == 0 && blockIdx.x != 0) return;
  const ushort_t* A = (z == 2) ? cs0_old : cs1_old;
  const ushort_t* B = (z == 0) ? w2b : (z == 1 ? w1tb : w1b);
  int n0 = blockIdx.x * 64;
  int g = blockIdx.y;          // batches g*32 .. g*32+31
  int m0 = g * 64;

  __shared__ ushort_t lds[2][2][4096];   // 32 KB
  int tid = threadIdx.x, wave = tid >> 6, lane = tid & 63;
  int wr = wave >> 1, wc = wave & 1;

  f32x4 acc[2][2];
#pragma unroll
  for (int m = 0; m < 2; ++m)
#pragma unroll
    for (int n = 0; n < 2; ++n) acc[m][n] = (f32x4)0.f;

  int srow = tid >> 3;
  int sg = tid & 7;

  auto stage = [&](int buf, int k0q) {
#pragma unroll
    for (int rseg = 0; rseg < 2; ++rseg) {
      int row = rseg * 32 + srow;
      int gsrc = (sg ^ (row & 7)) * 8;
      gload16(A + (size_t)(m0 + row) * DIM + k0q + gsrc, &lds[buf][0][row * 64 + sg * 8]);
      gload16(B + (size_t)(n0 + row) * DIM + k0q + gsrc, &lds[buf][1][row * 64 + sg * 8]);
    }
  };

  stage(0, 0);
  int cur = 0;
  for (int kt = 0; kt < 32; ++kt) {
    if (kt + 1 < 32) {
      stage(cur ^ 1, (kt + 1) * 64);
      asm volatile("s_waitcnt vmcnt(4)" ::: "memory");   // cur filled; prefetch in flight
    } else {
      asm volatile("s_waitcnt vmcnt(0)" ::: "memory");
    }
    __builtin_amdgcn_s_barrier();
    const ushort_t* la = lds[cur][0];
    const ushort_t* lb = lds[cur][1];
    int rowa = wr * 32 + (lane & 15);
    int rowb = wc * 32 + (lane & 15);
    int gl = lane >> 4;
#pragma unroll
    for (int kk = 0; kk < 64; kk += 32) {
      int kg = kk >> 3;
      int ga = ((gl + kg) ^ (rowa & 7)) * 8;
      int gb = ((gl + kg) ^ (rowb & 7)) * 8;
      short8 af0 = *(const short8*)&la[rowa * 64 + ga];
      short8 af1 = *(const short8*)&la[(rowa + 16) * 64 + ga];
      short8 bf0 = *(const short8*)&lb[rowb * 64 + gb];
      short8 bf1 = *(const short8*)&lb[(rowb + 16) * 64 + gb];
      acc[0][0] = __builtin_amdgcn_mfma_f32_16x16x32_bf16(af0, bf0, acc[0][0], 0, 0, 0);
      acc[0][1] = __builtin_amdgcn_mfma_f32_16x16x32_bf16(af0, bf1, acc[0][1], 0, 0, 0);
      acc[1][0] = __builtin_amdgcn_mfma_f32_16x16x32_bf16(af1, bf0, acc[1][0], 0, 0, 0);
      acc[1][1] = __builtin_amdgcn_mfma_f32_16x16x32_bf16(af1, bf1, acc[1][1], 0, 0, 0);
    }
    asm volatile("s_waitcnt lgkmcnt(0)" ::: "memory");
    __builtin_amdgcn_s_barrier();
    cur ^= 1;
  }

  // ---- epilogue: exchange P (rows 0..31 = cos part) / Q (rows 32..63 = sin) --
  float* ldsF = (float*)lds;   // [64][65] f32 = 16.6 KB, fits in the 32 KB
#pragma unroll
  for (int m = 0; m < 2; ++m)
#pragma unroll
    for (int n = 0; n < 2; ++n)
#pragma unroll
      for (int r = 0; r < 4; ++r)
        ldsF[(wr * 32 + m * 16 + (lane >> 4) * 4 + r) * 65 +
             wc * 32 + n * 16 + (lane & 15)] = acc[m][n][r];
  __syncthreads();

  int c4 = (tid & 15) * 4;
  int jg = n0 + c4;

  if (z == 0) {
    if (c4 < 12) {
#pragma unroll
      for (int bb = 0; bb < 2; ++bb) {
        int bl = (tid >> 4) * 2 + bb;
        int b = g * 32 + bl;
        int yb = y[b];
#pragma unroll
        for (int i = 0; i < 4; ++i) {
          int j = c4 + i;
          if (j < NCLS) {
            float u2c = ldsF[bl * 65 + j];
            float u2s = ldsF[(bl + 32) * 65 + j];
            size_t oi = (size_t)b * OUTSTRIDE + 2 * DIM + j;
            float phi = out[oi];
            float s, c;
            __sincosf(phi, &s, &c);
            float y1h = (yb == j) ? 1.f : -1.f;
            float gr = (u2c + b2[j]) * s - u2s * c + k2[j] * 2.f * s * c
                       - 0.5f * (c - y1h) * s;
            float pn = phi - 0.1f * gr;
            out[oi] = pn;
            __sincosf(pn, &s, &c);
            t2_new[b * 32 + j] = c;
            t2_new[b * 32 + 16 + j] = s;
          }
        }
      }
    }
    return;
  }

  ushort_t* csn = (z == 1) ? cs0_new : cs1_new;
  const float* bb_ = (z == 1) ? b0 : b1;
  const float* kk_ = (z == 1) ? k0 : k1;
  f32x4 bv = *(const f32x4*)&bb_[jg];
  f32x4 kv = *(const f32x4*)&kk_[jg];
  size_t oofs = (z == 1) ? 0 : (size_t)DIM;

#pragma unroll
  for (int bb = 0; bb < 2; ++bb) {
    int bl = (tid >> 4) * 2 + bb;
    int b = g * 32 + bl;
    f32x4 P, Q;
#pragma unroll
    for (int i = 0; i < 4; ++i) {
      P[i] = ldsF[bl * 65 + c4 + i];
      Q[i] = ldsF[(bl + 32) * 65 + c4 + i];
    }
    f32x4 uc, us;
    if (z == 1) {
      f32x4 av = *(const f32x4*)&a0p[(size_t)b * DIM + jg];
      f32x4 av1 = *(const f32x4*)&a0p[(size_t)BATCH * DIM + (size_t)b * DIM + jg];
      av += av1;
      uc = P + av + bv;
      us = Q;
    } else {
      f32x4 tc = (f32x4)0.f, ts = (f32x4)0.f;
#pragma unroll
      for (int q = 0; q < NCLS; ++q) {
        f32x4 wv = *(const f32x4*)&W2[q * DIM + jg];
        tc += t2_old[b * 32 + q] * wv;
        ts += t2_old[b * 32 + 16 + q] * wv;
      }
      uc = P + tc + bv;
      us = Q + ts;
    }
    float* po = &out[(size_t)b * OUTSTRIDE + oofs + jg];
    f32x4 ph = *(const f32x4*)po;
    ushort4v cv, sv;
#pragma unroll
    for (int i = 0; i < 4; ++i) {
      float s, c;
      __sincosf(ph[i], &s, &c);
      float gr = uc[i] * s - us[i] * c + kv[i] * 2.f * s * c;
      float pn = ph[i] - 0.1f * gr;
      ph[i] = pn;
      __sincosf(pn, &s, &c);
      cv[i] = f2bf(c);
      sv[i] = f2bf(s);
    }
    *(f32x4*)po = ph;
    int rc = g * 64 + bl;
    *(ushort4v*)&csn[(size_t)rc * DIM + jg] = cv;
    *(ushort4v*)&csn[(size_t)(rc + 32) * DIM + jg] = sv;
  }
}

// ---------------- launch ----------------
extern "C" void kernel_launch(void* const* d_in, const int* in_sizes, int n_in,
                              void* d_out, int out_size, void* d_ws, size_t ws_size,
                              hipStream_t stream) {
  const float* x    = (const float*)d_in[0];
  const float* W0   = (const float*)d_in[1];
  const float* W1   = (const float*)d_in[2];
  const float* W2   = (const float*)d_in[3];
  const float* b0   = (const float*)d_in[4];
  const float* b1   = (const float*)d_in[5];
  const float* b2   = (const float*)d_in[6];
  const float* k0   = (const float*)d_in[7];
  const float* k1   = (const float*)d_in[8];
  const float* k2   = (const float*)d_in[9];
  const float* phi0 = (const float*)d_in[10];
  const float* phi1 = (const float*)d_in[11];
  const float* phi2 = (const float*)d_in[12];
  const int*   y    = (const int*)d_in[13];
  float* out = (float*)d_out;

  const size_t CS = (size_t)2 * BATCH * DIM;   // 512*2048 elems per cs buffer

  char* w = (char*)d_ws;
  ushort_t* w0b  = (ushort_t*)w; w += (size_t)DIM * DIM * 2;
  ushort_t* w1b  = (ushort_t*)w; w += (size_t)DIM * DIM * 2;
  ushort_t* w1tb = (ushort_t*)w; w += (size_t)DIM * DIM * 2;
  ushort_t* w2b  = (ushort_t*)w; w += (size_t)64 * DIM * 2;
  ushort_t* xb   = (ushort_t*)w; w += (size_t)BATCH * DIM * 2;
  ushort_t* csi0 = (ushort_t*)w; w += 2 * CS * 2;
  ushort_t* csi1 = (ushort_t*)w; w += 2 * CS * 2;
  float* a0p = (float*)w; w += (size_t)2 * BATCH * DIM * 4;
  float* t2  = (float*)w; w += (size_t)2 * BATCH * 32 * 4;

  setup_all<<<8064, 256, 0, stream>>>(W0, w0b, x, xb, W2, w2b, W1, w1b, w1tb,
                                      phi0, phi1, phi2, out, csi0, csi1, t2);

  gemm_a0<<<dim3(32, 4, 2), 256, 0, stream>>>(xb, w0b, a0p);

  for (int t = 0; t < TSTEPS; ++t) {
    int r = t & 1, wv = r ^ 1;
    fused_iter<<<dim3(32, 8, 3), 256, 0, stream>>>(
        csi0 + r * CS, csi1 + r * CS, csi0 + wv * CS, csi1 + wv * CS,
        w1tb, w1b, w2b, a0p, b0, k0, b1, k1, b2, k2, W2, y,
        t2 + r * BATCH * 32, t2 + wv * BATCH * 32, out);
  }
}